// Round 13
// baseline (493.335 us; speedup 1.0000x reference)
//
#include <hip/hip_runtime.h>
#include <stdint.h>

#define RES   320
#define CCH   48
#define PW    321                  // padded pair-index width: j = x0+1 in [0,320]
#define PH    322                  // rows jy in [0,321]; rows 0 and 321 are zero
#define PS    (PH*PW*CCH)          // uints per transposed plane (4,961,376)
#define LS    (PW*CCH)             // uints per transposed line  (15,408)
#define KB    512                  // 8^3 Morton cells
#define SBP   8192                 // points per superblock

typedef _Float16 v2h __attribute__((ext_vector_type(2)));
typedef float    f4v __attribute__((ext_vector_type(4)));
typedef uint32_t u4v __attribute__((ext_vector_type(4)));

__device__ __forceinline__ v2h bch(uint32_t u) { return __builtin_bit_cast(v2h, u); }
__device__ __forceinline__ int clampi(int v, int lo, int hi) { return v < lo ? lo : (v > hi ? hi : v); }

#if __has_builtin(__builtin_amdgcn_fdot2)
__device__ __forceinline__ float fdot2f(v2h a, v2h b, float c) {
  return __builtin_amdgcn_fdot2(a, b, c, false);
}
#else
__device__ __forceinline__ float fdot2f(v2h a, v2h b, float c) {
  return fmaf((float)a.x, (float)b.x, fmaf((float)a.y, (float)b.y, c));
}
#endif

#if __has_builtin(__builtin_amdgcn_cvt_pkrtz)
__device__ __forceinline__ v2h pkw(float a, float b) {
  return __builtin_bit_cast(v2h, __builtin_amdgcn_cvt_pkrtz(a, b));
}
#else
__device__ __forceinline__ v2h pkw(float a, float b) { v2h r; r.x = (_Float16)a; r.y = (_Float16)b; return r; }
#endif

__device__ __forceinline__ uint16_t h16(float a) {
  return __builtin_bit_cast(uint16_t, (_Float16)a);
}

__device__ __forceinline__ void nt_store4(float* p, f4v v) {
  __builtin_nontemporal_store(v, (f4v*)p);
}

// ---------------- Morton key: 3 bits/axis, 512 cells ----------------
__device__ __forceinline__ uint32_t part1by2(uint32_t x) {
  x &= 0x3FF;
  x = (x | (x << 16)) & 0x030000FF;
  x = (x | (x << 8))  & 0x0300F00F;
  x = (x | (x << 4))  & 0x030C30C3;
  x = (x | (x << 2))  & 0x09249249;
  return x;
}
__device__ __forceinline__ uint32_t cellkey(float x, float y, float z) {
  int cx = clampi((int)fmaf(x, 4.f, 4.f), 0, 7);
  int cy = clampi((int)fmaf(y, 4.f, 4.f), 0, 7);
  int cz = clampi((int)fmaf(z, 4.f, 4.f), 0, 7);
  return part1by2((uint32_t)cx) | (part1by2((uint32_t)cy) << 1) | (part1by2((uint32_t)cz) << 2);
}

// ---- fused prep: planes (y=0..2), lines (y=3), per-superblock hist (y=4) ----
__global__ __launch_bounds__(256) void prep_all(const float* __restrict__ pyz,
                                                const float* __restrict__ pzx,
                                                const float* __restrict__ pxy,
                                                const float* __restrict__ lx,
                                                const float* __restrict__ ly,
                                                const float* __restrict__ lz,
                                                uint32_t* __restrict__ dst,
                                                const float* __restrict__ coords,
                                                uint32_t* __restrict__ hb,
                                                int npts, int nsb) {
  __shared__ __align__(16) char smem[322 * 50 * 2];   // union: lsh (32.2KB) / lh (2KB)
  int tid = threadIdx.x;
  int plane = blockIdx.y;

  if (plane == 4) {                 // per-superblock LDS histogram
    if (hb == nullptr) return;
    int sb = blockIdx.x;
    if (sb >= nsb) return;
    uint32_t* lh = (uint32_t*)smem;
    for (int i = tid; i < KB; i += 256) lh[i] = 0u;
    __syncthreads();
    int base = sb * SBP;
#pragma unroll 4
    for (int k = 0; k < SBP / 256; k++) {
      int p = base + k * 256 + tid;
      if (p < npts) {
        float x = coords[p * 3 + 0], y = coords[p * 3 + 1], z = coords[p * 3 + 2];
        atomicAdd(&lh[cellkey(x, y, z)], 1u);
      }
    }
    __syncthreads();
    uint32_t* d = hb + (size_t)sb * KB;
    for (int i = tid; i < KB; i += 256) d[i] = lh[i];
    return;
  }

  if (plane == 3) {                 // pack lines
    int idx = blockIdx.x * 256 + tid;        // line entries: 3 * PW = 963
    if (idx >= 3 * PW) return;
    int which = idx / PW;
    int j = idx - which * PW;
    const float* src = (which == 0) ? lx : ((which == 1) ? ly : lz);
    uint32_t* d = dst + 3 * (size_t)PS + (size_t)which * LS + (size_t)j * CCH;
    int  y0 = j - 1;
    bool v0 = (y0 >= 0);
    bool v1 = (j < RES);
#pragma unroll
    for (int c = 0; c < CCH; c++) {
      float a = v0 ? src[c * RES + y0] : 0.f;
      float b = v1 ? src[c * RES + j] : 0.f;
      d[c] = (uint32_t)h16(a) | ((uint32_t)h16(b) << 16);
    }
    return;
  }

  int jy = blockIdx.x;              // 0..PH-1
  const float* src = (plane == 0) ? pyz : ((plane == 1) ? pzx : pxy);
  uint32_t* d = dst + (size_t)plane * PS + (size_t)jy * PW * CCH;
  int y = jy - 1;

  if ((unsigned)y >= (unsigned)RES) {           // zero row
    for (int i = tid; i < PW * (CCH / 4); i += 256)
      *(uint4*)(d + i * 4) = make_uint4(0u, 0u, 0u, 0u);
    return;
  }

  // lsh[s][c]: s = x+1 in [0,321], sentinel rows 0 and 321 are zero. stride 50.
  _Float16* lsh = (_Float16*)smem;
  if (tid < 50) { lsh[tid] = (_Float16)0.f; lsh[321 * 50 + tid] = (_Float16)0.f; }
  for (int i = tid; i < CCH * RES; i += 256) {
    int c = i / RES;
    int x = i - c * RES;
    lsh[(x + 1) * 50 + c] = (_Float16)src[(size_t)c * RES * RES + (size_t)y * RES + x];
  }
  __syncthreads();

  // pack: entry (jx, c) = (v[x=jx-1], v[x=jx]) = (lsh[jx][c], lsh[jx+1][c])
  for (int i = tid; i < PW * (CCH / 4); i += 256) {
    int jx = i / (CCH / 4);
    int cb = (i - jx * (CCH / 4)) * 4;
    const _Float16* lo = &lsh[jx * 50 + cb];
    const _Float16* hi = &lsh[(jx + 1) * 50 + cb];
    uint32_t w[4];
#pragma unroll
    for (int k = 0; k < 4; k++)
      w[k] = (uint32_t)__builtin_bit_cast(uint16_t, lo[k]) |
             ((uint32_t)__builtin_bit_cast(uint16_t, hi[k]) << 16);
    *(uint4*)(d + (size_t)(jx * CCH + cb)) = make_uint4(w[0], w[1], w[2], w[3]);
  }
}

// Phase B1: per-bin running prefix across superblocks; emit totals T[bin]
__global__ __launch_bounds__(256) void scan_cols(uint32_t* __restrict__ hb,
                                                 uint32_t* __restrict__ T, int nsb) {
  int b = blockIdx.x * 256 + threadIdx.x;     // bin id
  if (b >= KB) return;
  uint32_t run = 0;
  for (int sb = 0; sb < nsb; sb++) {
    size_t idx = (size_t)sb * KB + b;
    uint32_t v = hb[idx];
    hb[idx] = run;                             // exclusive prefix over superblocks
    run += v;
  }
  T[b] = run;
}

// Phase B2: exclusive scan of T[KB] -> S[KB] (one block)
__global__ __launch_bounds__(256) void scan_T(const uint32_t* __restrict__ T,
                                              uint32_t* __restrict__ S) {
  __shared__ uint32_t bs[256];
  int tid = threadIdx.x;
  uint32_t loc[KB / 256];
  uint32_t s = 0;
#pragma unroll
  for (int k = 0; k < KB / 256; k++) { loc[k] = T[tid * (KB / 256) + k]; s += loc[k]; }
  bs[tid] = s;
  __syncthreads();
  for (int off = 1; off < 256; off <<= 1) {
    uint32_t u = (tid >= off) ? bs[tid - off] : 0u;
    __syncthreads();
    bs[tid] += u;
    __syncthreads();
  }
  uint32_t ex = tid ? bs[tid - 1] : 0u;
#pragma unroll
  for (int k = 0; k < KB / 256; k++) { S[tid * (KB / 256) + k] = ex; ex += loc[k]; }
}

// Phase C: scatter with LDS counters seeded S[bin] + hb[sb][bin]; NT stream-out
__global__ __launch_bounds__(256) void scatter_sb(const float* __restrict__ coords,
                                                  const uint32_t* __restrict__ hb,
                                                  const uint32_t* __restrict__ S,
                                                  uint32_t* __restrict__ sorted, int npts) {
  __shared__ uint32_t cnt[KB];
  int sb = blockIdx.x, tid = threadIdx.x;
  const uint32_t* row = hb + (size_t)sb * KB;
  for (int i = tid; i < KB; i += 256) cnt[i] = row[i] + S[i];
  __syncthreads();
  int base = sb * SBP;
#pragma unroll 4
  for (int k = 0; k < SBP / 256; k++) {
    int p = base + k * 256 + tid;
    if (p < npts) {
      float x = coords[p * 3 + 0], y = coords[p * 3 + 1], z = coords[p * 3 + 2];
      uint32_t pos = atomicAdd(&cnt[cellkey(x, y, z)], 1u);
      if (pos < (uint32_t)npts) {   // guard: corruption -> wrong answer, not OOB write
        u4v o = { __builtin_bit_cast(uint32_t, x),
                  __builtin_bit_cast(uint32_t, y),
                  __builtin_bit_cast(uint32_t, z),
                  (uint32_t)p };
        __builtin_nontemporal_store(o, (u4v*)(sorted + (size_t)pos * 4));
      }
    }
  }
}

// -------- per-plane sampling params (pointers + packed weights) --------
struct PP {
  const uint32_t* rA;
  const uint32_t* rB;
  const uint32_t* lr;
  v2h W0, W1, WT;
};

__device__ __forceinline__ PP mkpp(const uint32_t* __restrict__ P,
                                   const uint32_t* __restrict__ L,
                                   float gx, float gy, float tt) {
  float ix = fmaf(gx, 160.f, 159.5f);
  float fx = floorf(ix); float wx = ix - fx; int jx = clampi((int)fx + 1, 0, 320);
  float iy = fmaf(gy, 160.f, 159.5f);
  float fy = floorf(iy); float wy = iy - fy; int jy = clampi((int)fy + 1, 0, 320);
  float it = fmaf(tt, 160.f, 159.5f);
  float ft = floorf(it); float wt = it - ft; int jt = clampi((int)ft + 1, 0, 320);
  float omx = 1.f - wx, omy = 1.f - wy;
  PP p;
  p.W0 = pkw(omx * omy, wx * omy);
  p.W1 = pkw(omx * wy, wx * wy);
  p.WT = pkw(1.f - wt, wt);
  p.rA = P + (size_t)(jy * PW + jx) * CCH;
  p.rB = p.rA + PW * CCH;
  p.lr = L + (size_t)jt * CCH;
  return p;
}

// per-channel-quad accumulate for one plane
#define ACC4(A, B, LV, W0_, W1_, WT_, ai)                                   \
  {                                                                          \
    float s, lv;                                                             \
    s = fdot2f(bch((A).x), (W0_), 0.f); s = fdot2f(bch((B).x), (W1_), s);    \
    lv = fdot2f(bch((LV).x), (WT_), 0.f); acc[(ai)+0] = fmaf(s, lv, acc[(ai)+0]); \
    s = fdot2f(bch((A).y), (W0_), 0.f); s = fdot2f(bch((B).y), (W1_), s);    \
    lv = fdot2f(bch((LV).y), (WT_), 0.f); acc[(ai)+1] = fmaf(s, lv, acc[(ai)+1]); \
    s = fdot2f(bch((A).z), (W0_), 0.f); s = fdot2f(bch((B).z), (W1_), s);    \
    lv = fdot2f(bch((LV).z), (WT_), 0.f); acc[(ai)+2] = fmaf(s, lv, acc[(ai)+2]); \
    s = fdot2f(bch((A).w), (W0_), 0.f); s = fdot2f(bch((B).w), (W1_), s);    \
    lv = fdot2f(bch((LV).w), (WT_), 0.f); acc[(ai)+3] = fmaf(s, lv, acc[(ai)+3]); \
  }

// ---------------- main: 4 lanes/point, direct full-line NT stores ----------------
// 36 KB LDS ballast caps residency at 4 blocks/CU: resident spread = 4*32*64
// = 8K pts/XCD -> 3-plane gather window ~2 MB, fits 4 MB L2 (vs 16K/4 MB at 8).
__global__ __launch_bounds__(256) void tensorf_sorted4(const uint4* __restrict__ sp,
                                                       const uint32_t* __restrict__ ws,
                                                       float* __restrict__ out,
                                                       int npts, int nwg) {
  __shared__ float ballast[9216];     // 36 KB occupancy cap (4 blocks/CU)
  int cpx = nwg >> 3;
  int bid = blockIdx.x;
  int swz = (bid & 7) * cpx + (bid >> 3);     // XCD k owns contiguous sorted chunk
  int tid = threadIdx.x;
  int pt = tid >> 2;                  // point slot in block (0..63)
  int q  = tid & 3;                   // lane within point
  int i  = swz * 64 + pt;             // sorted point index
  if (nwg < 0) {                      // never true; opaque -> ballast not DCE'd
    ballast[tid] = (float)tid;
    __syncthreads();
    out[tid] = ballast[255 - tid];
    return;
  }
  if (i >= npts) return;

  uint4 s4 = sp[i];
  float x = __builtin_bit_cast(float, s4.x);
  float y = __builtin_bit_cast(float, s4.y);
  float z = __builtin_bit_cast(float, s4.z);
  int pid = (int)s4.w;
  if ((unsigned)pid >= (unsigned)npts) return;   // guard: no OOB write ever

  const uint32_t* P0 = ws;
  const uint32_t* P1 = ws + PS;
  const uint32_t* P2 = ws + 2 * (size_t)PS;
  const uint32_t* L0 = ws + 3 * (size_t)PS;
  const uint32_t* L1 = L0 + LS;
  const uint32_t* L2 = L1 + LS;

  PP p0 = mkpp(P0, L0, y, z, x);   // plane_yz: gx=y, gy=z; line_x(t=x)
  PP p1 = mkpp(P1, L1, z, x, y);   // plane_zx: gx=z, gy=x; line_y(t=y)
  PP p2 = mkpp(P2, L2, x, y, z);   // plane_xy: gx=x, gy=y; line_z(t=z)

  float acc[12];
#pragma unroll
  for (int k = 0; k < 12; k++) acc[k] = 0.f;

#pragma unroll
  for (int j = 0; j < 3; j++) {
    int off = (4 * j + q) * 4;        // 4 lanes cover one 64B line per row per j
    uint4 a0 = *(const uint4*)(p0.rA + off);
    uint4 b0 = *(const uint4*)(p0.rB + off);
    uint4 l0 = *(const uint4*)(p0.lr + off);
    uint4 a1 = *(const uint4*)(p1.rA + off);
    uint4 b1 = *(const uint4*)(p1.rB + off);
    uint4 l1 = *(const uint4*)(p1.lr + off);
    uint4 a2 = *(const uint4*)(p2.rA + off);
    uint4 b2 = *(const uint4*)(p2.rB + off);
    uint4 l2 = *(const uint4*)(p2.lr + off);
    int ai = j * 4;
    ACC4(a0, b0, l0, p0.W0, p0.W1, p0.WT, ai);
    ACC4(a1, b1, l1, p1.W0, p1.W1, p1.WT, ai);
    ACC4(a2, b2, l2, p2.W0, p2.W1, p2.WT, ai);
  }

  // direct NT stores: for fixed j, the 4 lanes of this point write one full
  // 64B line. No LDS staging, no write amplification.
  float* o = out + (size_t)pid * CCH;
#pragma unroll
  for (int j = 0; j < 3; j++) {
    f4v v = { acc[j * 4 + 0], acc[j * 4 + 1], acc[j * 4 + 2], acc[j * 4 + 3] };
    nt_store4(o + (4 * j + q) * 4, v);
  }
}

// ---------------- main (unsorted fallback, proven path, 2 lanes/pt) ----------------
__global__ __launch_bounds__(256) void tensorf_main(const float* __restrict__ coords,
                                                    const uint32_t* __restrict__ ws,
                                                    float* __restrict__ out, int npts) {
  int t = blockIdx.x * 256 + threadIdx.x;
  int pid = t >> 1;
  int q = t & 1;
  if (pid >= npts) return;
  float x = coords[pid * 3 + 0];
  float y = coords[pid * 3 + 1];
  float z = coords[pid * 3 + 2];

  const uint32_t* P0 = ws;
  const uint32_t* P1 = ws + PS;
  const uint32_t* P2 = ws + 2 * (size_t)PS;
  const uint32_t* L0 = ws + 3 * (size_t)PS;
  const uint32_t* L1 = L0 + LS;
  const uint32_t* L2 = L1 + LS;

  PP p0 = mkpp(P0, L0, y, z, x);
  PP p1 = mkpp(P1, L1, z, x, y);
  PP p2 = mkpp(P2, L2, x, y, z);

  float acc[24];
#pragma unroll
  for (int k = 0; k < 24; k++) acc[k] = 0.f;

#pragma unroll
  for (int j = 0; j < 6; j++) {
    int off = (2 * j + q) * 4;
    uint4 a0 = *(const uint4*)(p0.rA + off);
    uint4 b0 = *(const uint4*)(p0.rB + off);
    uint4 l0 = *(const uint4*)(p0.lr + off);
    uint4 a1 = *(const uint4*)(p1.rA + off);
    uint4 b1 = *(const uint4*)(p1.rB + off);
    uint4 l1 = *(const uint4*)(p1.lr + off);
    uint4 a2 = *(const uint4*)(p2.rA + off);
    uint4 b2 = *(const uint4*)(p2.rB + off);
    uint4 l2 = *(const uint4*)(p2.lr + off);
    int ai = j * 4;
    ACC4(a0, b0, l0, p0.W0, p0.W1, p0.WT, ai);
    ACC4(a1, b1, l1, p1.W0, p1.W1, p1.WT, ai);
    ACC4(a2, b2, l2, p2.W0, p2.W1, p2.WT, ai);
  }

  float4* o = (float4*)(out + (size_t)pid * CCH);
#pragma unroll
  for (int j = 0; j < 6; j++) {
    float4 v;
    v.x = acc[j * 4 + 0]; v.y = acc[j * 4 + 1];
    v.z = acc[j * 4 + 2]; v.w = acc[j * 4 + 3];
    o[2 * j + q] = v;
  }
}

// ---------------- direct fallback (tiny ws): slow, correct ----------------
__device__ __forceinline__ float bil(const float* __restrict__ p, int x0, int y0, float wx, float wy) {
  int x1 = x0 + 1, y1 = y0 + 1;
  bool bx0 = (unsigned)x0 < (unsigned)RES, bx1 = (unsigned)x1 < (unsigned)RES;
  bool by0 = (unsigned)y0 < (unsigned)RES, by1 = (unsigned)y1 < (unsigned)RES;
  float v00 = 0.f, v01 = 0.f, v10 = 0.f, v11 = 0.f;
  if (by0) { const float* r = p + (size_t)y0 * RES; if (bx0) v00 = r[x0]; if (bx1) v01 = r[x1]; }
  if (by1) { const float* r = p + (size_t)y1 * RES; if (bx0) v10 = r[x0]; if (bx1) v11 = r[x1]; }
  return v00 * (1.f - wx) * (1.f - wy) + v01 * wx * (1.f - wy) + v10 * (1.f - wx) * wy + v11 * wx * wy;
}
__device__ __forceinline__ float lin1(const float* __restrict__ l, int y0, float wy) {
  int y1 = y0 + 1;
  float a = ((unsigned)y0 < (unsigned)RES) ? l[y0] : 0.f;
  float b = ((unsigned)y1 < (unsigned)RES) ? l[y1] : 0.f;
  return a * (1.f - wy) + b * wy;
}
__global__ __launch_bounds__(256) void tensorf_fallback(const float* __restrict__ coords,
    const float* __restrict__ pyz, const float* __restrict__ pzx, const float* __restrict__ pxy,
    const float* __restrict__ lx, const float* __restrict__ ly, const float* __restrict__ lz,
    float* __restrict__ out, int npts) {
  int pid = blockIdx.x * 256 + threadIdx.x;
  if (pid >= npts) return;
  float x = coords[pid * 3 + 0], y = coords[pid * 3 + 1], z = coords[pid * 3 + 2];
  float ixs[3], iys[3], its[3];
  ixs[0] = fmaf(y, 160.f, 159.5f); iys[0] = fmaf(z, 160.f, 159.5f); its[0] = fmaf(x, 160.f, 159.5f);
  ixs[1] = fmaf(z, 160.f, 159.5f); iys[1] = fmaf(x, 160.f, 159.5f); its[1] = fmaf(y, 160.f, 159.5f);
  ixs[2] = fmaf(x, 160.f, 159.5f); iys[2] = fmaf(y, 160.f, 159.5f); its[2] = fmaf(z, 160.f, 159.5f);
  int x0[3], y0[3], t0[3]; float wx[3], wyv[3], wt[3];
#pragma unroll
  for (int p = 0; p < 3; p++) {
    float fx = floorf(ixs[p]); wx[p] = ixs[p] - fx; x0[p] = (int)fx;
    float fy = floorf(iys[p]); wyv[p] = iys[p] - fy; y0[p] = (int)fy;
    float ft = floorf(its[p]); wt[p] = its[p] - ft; t0[p] = (int)ft;
  }
  const float* planes[3] = { pyz, pzx, pxy };
  const float* lines[3]  = { lx, ly, lz };
  for (int c = 0; c < CCH; c++) {
    float f = 0.f;
#pragma unroll
    for (int p = 0; p < 3; p++) {
      float pv = bil(planes[p] + (size_t)c * RES * RES, x0[p], y0[p], wx[p], wyv[p]);
      float lv = lin1(lines[p] + (size_t)c * RES, t0[p], wt[p]);
      f = fmaf(pv, lv, f);
    }
    out[(size_t)pid * CCH + c] = f;
  }
}

extern "C" void kernel_launch(void* const* d_in, const int* in_sizes, int n_in,
                              void* d_out, int out_size, void* d_ws, size_t ws_size,
                              hipStream_t stream) {
  const float* coords = (const float*)d_in[0];
  const float* pyz = (const float*)d_in[1];
  const float* pzx = (const float*)d_in[2];
  const float* pxy = (const float*)d_in[3];
  const float* lx  = (const float*)d_in[4];
  const float* ly  = (const float*)d_in[5];
  const float* lz  = (const float*)d_in[6];
  float* out = (float*)d_out;
  int npts = in_sizes[0] / 3;

  int nsb = (npts + SBP - 1) / SBP;                          // superblocks
  size_t tablesU = 3 * (size_t)PS + 3 * (size_t)LS;          // uints
  size_t needBase   = tablesU * 4u;                          // ~59.7 MB
  size_t needSorted = (tablesU + (size_t)nsb * KB + 2 * KB + (size_t)npts * 4) * 4u;

  if (ws_size >= needSorted) {
    uint32_t* ws = (uint32_t*)d_ws;
    uint32_t* hb = ws + tablesU;                             // [nsb][KB]
    uint32_t* T  = hb + (size_t)nsb * KB;                    // [KB]
    uint32_t* S  = T + KB;                                   // [KB]
    uint32_t* sorted = S + KB;                               // [npts*4]

    int gx = PH > nsb ? PH : nsb;
    prep_all<<<dim3(gx, 5), 256, 0, stream>>>(pyz, pzx, pxy, lx, ly, lz, ws,
                                              coords, hb, npts, nsb);
    scan_cols<<<(KB + 255) / 256, 256, 0, stream>>>(hb, T, nsb);
    scan_T<<<1, 256, 0, stream>>>(T, S);
    scatter_sb<<<nsb, 256, 0, stream>>>(coords, hb, S, sorted, npts);
    int nwg = (npts + 63) / 64;                              // 64 points per block (4 lanes/pt)
    nwg = (nwg + 7) & ~7;                                    // multiple of 8 for swizzle
    tensorf_sorted4<<<nwg, 256, 0, stream>>>((const uint4*)sorted, ws, out, npts, nwg);
  } else if (ws_size >= needBase) {
    uint32_t* ws = (uint32_t*)d_ws;
    prep_all<<<dim3(PH, 4), 256, 0, stream>>>(pyz, pzx, pxy, lx, ly, lz, ws,
                                              nullptr, nullptr, npts, 0);
    int nthreads = npts * 2;
    tensorf_main<<<(nthreads + 255) / 256, 256, 0, stream>>>(coords, ws, out, npts);
  } else {
    tensorf_fallback<<<(npts + 255) / 256, 256, 0, stream>>>(coords, pyz, pzx, pxy, lx, ly, lz, out, npts);
  }
}

// Round 14
// 465.491 us; speedup vs baseline: 1.0598x; 1.0598x over previous
//
#include <hip/hip_runtime.h>
#include <stdint.h>

#define RES   320
#define CCH   48
#define PW    321                  // padded pair-index width: j = x0+1 in [0,320]
#define PH    322                  // rows jy in [0,321]; rows 0 and 321 are zero
#define PS    (PH*PW*CCH)          // uints per transposed plane (4,961,376)
#define LS    (PW*CCH)             // uints per transposed line  (15,408)
#define KB    512                  // 8^3 Morton cells
#define SBP   8192                 // points per superblock

typedef _Float16 v2h __attribute__((ext_vector_type(2)));
typedef float    f4v __attribute__((ext_vector_type(4)));
typedef uint32_t u4v __attribute__((ext_vector_type(4)));

__device__ __forceinline__ v2h bch(uint32_t u) { return __builtin_bit_cast(v2h, u); }
__device__ __forceinline__ int clampi(int v, int lo, int hi) { return v < lo ? lo : (v > hi ? hi : v); }

#if __has_builtin(__builtin_amdgcn_fdot2)
__device__ __forceinline__ float fdot2f(v2h a, v2h b, float c) {
  return __builtin_amdgcn_fdot2(a, b, c, false);
}
#else
__device__ __forceinline__ float fdot2f(v2h a, v2h b, float c) {
  return fmaf((float)a.x, (float)b.x, fmaf((float)a.y, (float)b.y, c));
}
#endif

#if __has_builtin(__builtin_amdgcn_cvt_pkrtz)
__device__ __forceinline__ v2h pkw(float a, float b) {
  return __builtin_bit_cast(v2h, __builtin_amdgcn_cvt_pkrtz(a, b));
}
#else
__device__ __forceinline__ v2h pkw(float a, float b) { v2h r; r.x = (_Float16)a; r.y = (_Float16)b; return r; }
#endif

__device__ __forceinline__ uint16_t h16(float a) {
  return __builtin_bit_cast(uint16_t, (_Float16)a);
}

__device__ __forceinline__ void nt_store4(float* p, f4v v) {
  __builtin_nontemporal_store(v, (f4v*)p);
}

// ---------------- Morton key: 3 bits/axis, 512 cells ----------------
__device__ __forceinline__ uint32_t part1by2(uint32_t x) {
  x &= 0x3FF;
  x = (x | (x << 16)) & 0x030000FF;
  x = (x | (x << 8))  & 0x0300F00F;
  x = (x | (x << 4))  & 0x030C30C3;
  x = (x | (x << 2))  & 0x09249249;
  return x;
}
__device__ __forceinline__ uint32_t cellkey(float x, float y, float z) {
  int cx = clampi((int)fmaf(x, 4.f, 4.f), 0, 7);
  int cy = clampi((int)fmaf(y, 4.f, 4.f), 0, 7);
  int cz = clampi((int)fmaf(z, 4.f, 4.f), 0, 7);
  return part1by2((uint32_t)cx) | (part1by2((uint32_t)cy) << 1) | (part1by2((uint32_t)cz) << 2);
}

// ---- fused prep: planes (y=0..2), lines (y=3), per-superblock hist (y=4) ----
__global__ __launch_bounds__(256) void prep_all(const float* __restrict__ pyz,
                                                const float* __restrict__ pzx,
                                                const float* __restrict__ pxy,
                                                const float* __restrict__ lx,
                                                const float* __restrict__ ly,
                                                const float* __restrict__ lz,
                                                uint32_t* __restrict__ dst,
                                                const float* __restrict__ coords,
                                                uint32_t* __restrict__ hb,
                                                int npts, int nsb) {
  __shared__ __align__(16) char smem[322 * 50 * 2];   // union: lsh (32.2KB) / lh (2KB)
  int tid = threadIdx.x;
  int plane = blockIdx.y;

  if (plane == 4) {                 // per-superblock LDS histogram
    if (hb == nullptr) return;
    int sb = blockIdx.x;
    if (sb >= nsb) return;
    uint32_t* lh = (uint32_t*)smem;
    for (int i = tid; i < KB; i += 256) lh[i] = 0u;
    __syncthreads();
    int base = sb * SBP;
#pragma unroll 4
    for (int k = 0; k < SBP / 256; k++) {
      int p = base + k * 256 + tid;
      if (p < npts) {
        float x = coords[p * 3 + 0], y = coords[p * 3 + 1], z = coords[p * 3 + 2];
        atomicAdd(&lh[cellkey(x, y, z)], 1u);
      }
    }
    __syncthreads();
    uint32_t* d = hb + (size_t)sb * KB;
    for (int i = tid; i < KB; i += 256) d[i] = lh[i];
    return;
  }

  if (plane == 3) {                 // pack lines
    int idx = blockIdx.x * 256 + tid;        // line entries: 3 * PW = 963
    if (idx >= 3 * PW) return;
    int which = idx / PW;
    int j = idx - which * PW;
    const float* src = (which == 0) ? lx : ((which == 1) ? ly : lz);
    uint32_t* d = dst + 3 * (size_t)PS + (size_t)which * LS + (size_t)j * CCH;
    int  y0 = j - 1;
    bool v0 = (y0 >= 0);
    bool v1 = (j < RES);
#pragma unroll
    for (int c = 0; c < CCH; c++) {
      float a = v0 ? src[c * RES + y0] : 0.f;
      float b = v1 ? src[c * RES + j] : 0.f;
      d[c] = (uint32_t)h16(a) | ((uint32_t)h16(b) << 16);
    }
    return;
  }

  int jy = blockIdx.x;              // 0..PH-1
  const float* src = (plane == 0) ? pyz : ((plane == 1) ? pzx : pxy);
  uint32_t* d = dst + (size_t)plane * PS + (size_t)jy * PW * CCH;
  int y = jy - 1;

  if ((unsigned)y >= (unsigned)RES) {           // zero row
    for (int i = tid; i < PW * (CCH / 4); i += 256)
      *(uint4*)(d + i * 4) = make_uint4(0u, 0u, 0u, 0u);
    return;
  }

  // lsh[s][c]: s = x+1 in [0,321], sentinel rows 0 and 321 are zero. stride 50.
  _Float16* lsh = (_Float16*)smem;
  if (tid < 50) { lsh[tid] = (_Float16)0.f; lsh[321 * 50 + tid] = (_Float16)0.f; }
  for (int i = tid; i < CCH * RES; i += 256) {
    int c = i / RES;
    int x = i - c * RES;
    lsh[(x + 1) * 50 + c] = (_Float16)src[(size_t)c * RES * RES + (size_t)y * RES + x];
  }
  __syncthreads();

  // pack: entry (jx, c) = (v[x=jx-1], v[x=jx]) = (lsh[jx][c], lsh[jx+1][c])
  for (int i = tid; i < PW * (CCH / 4); i += 256) {
    int jx = i / (CCH / 4);
    int cb = (i - jx * (CCH / 4)) * 4;
    const _Float16* lo = &lsh[jx * 50 + cb];
    const _Float16* hi = &lsh[(jx + 1) * 50 + cb];
    uint32_t w[4];
#pragma unroll
    for (int k = 0; k < 4; k++)
      w[k] = (uint32_t)__builtin_bit_cast(uint16_t, lo[k]) |
             ((uint32_t)__builtin_bit_cast(uint16_t, hi[k]) << 16);
    *(uint4*)(d + (size_t)(jx * CCH + cb)) = make_uint4(w[0], w[1], w[2], w[3]);
  }
}

// Phase B1: per-bin running prefix across superblocks; emit totals T[bin]
__global__ __launch_bounds__(256) void scan_cols(uint32_t* __restrict__ hb,
                                                 uint32_t* __restrict__ T, int nsb) {
  int b = blockIdx.x * 256 + threadIdx.x;     // bin id
  if (b >= KB) return;
  uint32_t run = 0;
  for (int sb = 0; sb < nsb; sb++) {
    size_t idx = (size_t)sb * KB + b;
    uint32_t v = hb[idx];
    hb[idx] = run;                             // exclusive prefix over superblocks
    run += v;
  }
  T[b] = run;
}

// Phase C: scatter; global bin prefix S computed in-block from T (2KB, L2-hit)
__global__ __launch_bounds__(256) void scatter_sb(const float* __restrict__ coords,
                                                  const uint32_t* __restrict__ hb,
                                                  const uint32_t* __restrict__ T,
                                                  uint32_t* __restrict__ sorted, int npts) {
  __shared__ uint32_t cnt[KB];
  __shared__ uint32_t bs[256];
  int sb = blockIdx.x, tid = threadIdx.x;

  // exclusive prefix of T[512] into cnt (as S), 2 elems/thread
  uint32_t t0 = T[tid * 2], t1 = T[tid * 2 + 1];
  bs[tid] = t0 + t1;
  __syncthreads();
  for (int off = 1; off < 256; off <<= 1) {
    uint32_t u = (tid >= off) ? bs[tid - off] : 0u;
    __syncthreads();
    bs[tid] += u;
    __syncthreads();
  }
  uint32_t ex = tid ? bs[tid - 1] : 0u;
  const uint32_t* row = hb + (size_t)sb * KB;
  cnt[tid * 2]     = ex + row[tid * 2];
  cnt[tid * 2 + 1] = ex + t0 + row[tid * 2 + 1];
  __syncthreads();

  int base = sb * SBP;
#pragma unroll 4
  for (int k = 0; k < SBP / 256; k++) {
    int p = base + k * 256 + tid;
    if (p < npts) {
      float x = coords[p * 3 + 0], y = coords[p * 3 + 1], z = coords[p * 3 + 2];
      uint32_t pos = atomicAdd(&cnt[cellkey(x, y, z)], 1u);
      if (pos < (uint32_t)npts) {   // guard: corruption -> wrong answer, not OOB write
        u4v o = { __builtin_bit_cast(uint32_t, x),
                  __builtin_bit_cast(uint32_t, y),
                  __builtin_bit_cast(uint32_t, z),
                  (uint32_t)p };
        __builtin_nontemporal_store(o, (u4v*)(sorted + (size_t)pos * 4));
      }
    }
  }
}

// -------- per-plane sampling params (pointers + packed weights) --------
struct PP {
  const uint32_t* rA;
  const uint32_t* rB;
  const uint32_t* lr;
  v2h W0, W1, WT;
};

__device__ __forceinline__ PP mkpp(const uint32_t* __restrict__ P,
                                   const uint32_t* __restrict__ L,
                                   float gx, float gy, float tt) {
  float ix = fmaf(gx, 160.f, 159.5f);
  float fx = floorf(ix); float wx = ix - fx; int jx = clampi((int)fx + 1, 0, 320);
  float iy = fmaf(gy, 160.f, 159.5f);
  float fy = floorf(iy); float wy = iy - fy; int jy = clampi((int)fy + 1, 0, 320);
  float it = fmaf(tt, 160.f, 159.5f);
  float ft = floorf(it); float wt = it - ft; int jt = clampi((int)ft + 1, 0, 320);
  float omx = 1.f - wx, omy = 1.f - wy;
  PP p;
  p.W0 = pkw(omx * omy, wx * omy);
  p.W1 = pkw(omx * wy, wx * wy);
  p.WT = pkw(1.f - wt, wt);
  p.rA = P + (size_t)(jy * PW + jx) * CCH;
  p.rB = p.rA + PW * CCH;
  p.lr = L + (size_t)jt * CCH;
  return p;
}

// per-channel-quad accumulate for one plane
#define ACC4(A, B, LV, W0_, W1_, WT_, ai)                                   \
  {                                                                          \
    float s, lv;                                                             \
    s = fdot2f(bch((A).x), (W0_), 0.f); s = fdot2f(bch((B).x), (W1_), s);    \
    lv = fdot2f(bch((LV).x), (WT_), 0.f); acc[(ai)+0] = fmaf(s, lv, acc[(ai)+0]); \
    s = fdot2f(bch((A).y), (W0_), 0.f); s = fdot2f(bch((B).y), (W1_), s);    \
    lv = fdot2f(bch((LV).y), (WT_), 0.f); acc[(ai)+1] = fmaf(s, lv, acc[(ai)+1]); \
    s = fdot2f(bch((A).z), (W0_), 0.f); s = fdot2f(bch((B).z), (W1_), s);    \
    lv = fdot2f(bch((LV).z), (WT_), 0.f); acc[(ai)+2] = fmaf(s, lv, acc[(ai)+2]); \
    s = fdot2f(bch((A).w), (W0_), 0.f); s = fdot2f(bch((B).w), (W1_), s);    \
    lv = fdot2f(bch((LV).w), (WT_), 0.f); acc[(ai)+3] = fmaf(s, lv, acc[(ai)+3]); \
  }

// ---------------- main: 4 lanes/point, direct full-line NT stores (no LDS) ----------------
__global__ __launch_bounds__(256) void tensorf_sorted4(const uint4* __restrict__ sp,
                                                       const uint32_t* __restrict__ ws,
                                                       float* __restrict__ out,
                                                       int npts, int nwg) {
  int cpx = nwg >> 3;
  int bid = blockIdx.x;
  int swz = (bid & 7) * cpx + (bid >> 3);     // XCD k owns contiguous sorted chunk
  int tid = threadIdx.x;
  int pt = tid >> 2;                  // point slot in block (0..63)
  int q  = tid & 3;                   // lane within point
  int i  = swz * 64 + pt;             // sorted point index
  if (i >= npts) return;

  uint4 s4 = sp[i];
  float x = __builtin_bit_cast(float, s4.x);
  float y = __builtin_bit_cast(float, s4.y);
  float z = __builtin_bit_cast(float, s4.z);
  int pid = (int)s4.w;
  if ((unsigned)pid >= (unsigned)npts) return;   // guard: no OOB write ever

  const uint32_t* P0 = ws;
  const uint32_t* P1 = ws + PS;
  const uint32_t* P2 = ws + 2 * (size_t)PS;
  const uint32_t* L0 = ws + 3 * (size_t)PS;
  const uint32_t* L1 = L0 + LS;
  const uint32_t* L2 = L1 + LS;

  PP p0 = mkpp(P0, L0, y, z, x);   // plane_yz: gx=y, gy=z; line_x(t=x)
  PP p1 = mkpp(P1, L1, z, x, y);   // plane_zx: gx=z, gy=x; line_y(t=y)
  PP p2 = mkpp(P2, L2, x, y, z);   // plane_xy: gx=x, gy=y; line_z(t=z)

  float acc[12];
#pragma unroll
  for (int k = 0; k < 12; k++) acc[k] = 0.f;

#pragma unroll
  for (int j = 0; j < 3; j++) {
    int off = (4 * j + q) * 4;        // 4 lanes cover one 64B line per row per j
    uint4 a0 = *(const uint4*)(p0.rA + off);
    uint4 b0 = *(const uint4*)(p0.rB + off);
    uint4 l0 = *(const uint4*)(p0.lr + off);
    uint4 a1 = *(const uint4*)(p1.rA + off);
    uint4 b1 = *(const uint4*)(p1.rB + off);
    uint4 l1 = *(const uint4*)(p1.lr + off);
    uint4 a2 = *(const uint4*)(p2.rA + off);
    uint4 b2 = *(const uint4*)(p2.rB + off);
    uint4 l2 = *(const uint4*)(p2.lr + off);
    int ai = j * 4;
    ACC4(a0, b0, l0, p0.W0, p0.W1, p0.WT, ai);
    ACC4(a1, b1, l1, p1.W0, p1.W1, p1.WT, ai);
    ACC4(a2, b2, l2, p2.W0, p2.W1, p2.WT, ai);
  }

  // direct NT stores: for fixed j, the 4 lanes of this point write one full
  // 64B line. No LDS staging, no write amplification.
  float* o = out + (size_t)pid * CCH;
#pragma unroll
  for (int j = 0; j < 3; j++) {
    f4v v = { acc[j * 4 + 0], acc[j * 4 + 1], acc[j * 4 + 2], acc[j * 4 + 3] };
    nt_store4(o + (4 * j + q) * 4, v);
  }
}

// ---------------- main (unsorted fallback, proven path, 2 lanes/pt) ----------------
__global__ __launch_bounds__(256) void tensorf_main(const float* __restrict__ coords,
                                                    const uint32_t* __restrict__ ws,
                                                    float* __restrict__ out, int npts) {
  int t = blockIdx.x * 256 + threadIdx.x;
  int pid = t >> 1;
  int q = t & 1;
  if (pid >= npts) return;
  float x = coords[pid * 3 + 0];
  float y = coords[pid * 3 + 1];
  float z = coords[pid * 3 + 2];

  const uint32_t* P0 = ws;
  const uint32_t* P1 = ws + PS;
  const uint32_t* P2 = ws + 2 * (size_t)PS;
  const uint32_t* L0 = ws + 3 * (size_t)PS;
  const uint32_t* L1 = L0 + LS;
  const uint32_t* L2 = L1 + LS;

  PP p0 = mkpp(P0, L0, y, z, x);
  PP p1 = mkpp(P1, L1, z, x, y);
  PP p2 = mkpp(P2, L2, x, y, z);

  float acc[24];
#pragma unroll
  for (int k = 0; k < 24; k++) acc[k] = 0.f;

#pragma unroll
  for (int j = 0; j < 6; j++) {
    int off = (2 * j + q) * 4;
    uint4 a0 = *(const uint4*)(p0.rA + off);
    uint4 b0 = *(const uint4*)(p0.rB + off);
    uint4 l0 = *(const uint4*)(p0.lr + off);
    uint4 a1 = *(const uint4*)(p1.rA + off);
    uint4 b1 = *(const uint4*)(p1.rB + off);
    uint4 l1 = *(const uint4*)(p1.lr + off);
    uint4 a2 = *(const uint4*)(p2.rA + off);
    uint4 b2 = *(const uint4*)(p2.rB + off);
    uint4 l2 = *(const uint4*)(p2.lr + off);
    int ai = j * 4;
    ACC4(a0, b0, l0, p0.W0, p0.W1, p0.WT, ai);
    ACC4(a1, b1, l1, p1.W0, p1.W1, p1.WT, ai);
    ACC4(a2, b2, l2, p2.W0, p2.W1, p2.WT, ai);
  }

  float4* o = (float4*)(out + (size_t)pid * CCH);
#pragma unroll
  for (int j = 0; j < 6; j++) {
    float4 v;
    v.x = acc[j * 4 + 0]; v.y = acc[j * 4 + 1];
    v.z = acc[j * 4 + 2]; v.w = acc[j * 4 + 3];
    o[2 * j + q] = v;
  }
}

// ---------------- direct fallback (tiny ws): slow, correct ----------------
__device__ __forceinline__ float bil(const float* __restrict__ p, int x0, int y0, float wx, float wy) {
  int x1 = x0 + 1, y1 = y0 + 1;
  bool bx0 = (unsigned)x0 < (unsigned)RES, bx1 = (unsigned)x1 < (unsigned)RES;
  bool by0 = (unsigned)y0 < (unsigned)RES, by1 = (unsigned)y1 < (unsigned)RES;
  float v00 = 0.f, v01 = 0.f, v10 = 0.f, v11 = 0.f;
  if (by0) { const float* r = p + (size_t)y0 * RES; if (bx0) v00 = r[x0]; if (bx1) v01 = r[x1]; }
  if (by1) { const float* r = p + (size_t)y1 * RES; if (bx0) v10 = r[x0]; if (bx1) v11 = r[x1]; }
  return v00 * (1.f - wx) * (1.f - wy) + v01 * wx * (1.f - wy) + v10 * (1.f - wx) * wy + v11 * wx * wy;
}
__device__ __forceinline__ float lin1(const float* __restrict__ l, int y0, float wy) {
  int y1 = y0 + 1;
  float a = ((unsigned)y0 < (unsigned)RES) ? l[y0] : 0.f;
  float b = ((unsigned)y1 < (unsigned)RES) ? l[y1] : 0.f;
  return a * (1.f - wy) + b * wy;
}
__global__ __launch_bounds__(256) void tensorf_fallback(const float* __restrict__ coords,
    const float* __restrict__ pyz, const float* __restrict__ pzx, const float* __restrict__ pxy,
    const float* __restrict__ lx, const float* __restrict__ ly, const float* __restrict__ lz,
    float* __restrict__ out, int npts) {
  int pid = blockIdx.x * 256 + threadIdx.x;
  if (pid >= npts) return;
  float x = coords[pid * 3 + 0], y = coords[pid * 3 + 1], z = coords[pid * 3 + 2];
  float ixs[3], iys[3], its[3];
  ixs[0] = fmaf(y, 160.f, 159.5f); iys[0] = fmaf(z, 160.f, 159.5f); its[0] = fmaf(x, 160.f, 159.5f);
  ixs[1] = fmaf(z, 160.f, 159.5f); iys[1] = fmaf(x, 160.f, 159.5f); its[1] = fmaf(y, 160.f, 159.5f);
  ixs[2] = fmaf(x, 160.f, 159.5f); iys[2] = fmaf(y, 160.f, 159.5f); its[2] = fmaf(z, 160.f, 159.5f);
  int x0[3], y0[3], t0[3]; float wx[3], wyv[3], wt[3];
#pragma unroll
  for (int p = 0; p < 3; p++) {
    float fx = floorf(ixs[p]); wx[p] = ixs[p] - fx; x0[p] = (int)fx;
    float fy = floorf(iys[p]); wyv[p] = iys[p] - fy; y0[p] = (int)fy;
    float ft = floorf(its[p]); wt[p] = its[p] - ft; t0[p] = (int)ft;
  }
  const float* planes[3] = { pyz, pzx, pxy };
  const float* lines[3]  = { lx, ly, lz };
  for (int c = 0; c < CCH; c++) {
    float f = 0.f;
#pragma unroll
    for (int p = 0; p < 3; p++) {
      float pv = bil(planes[p] + (size_t)c * RES * RES, x0[p], y0[p], wx[p], wyv[p]);
      float lv = lin1(lines[p] + (size_t)c * RES, t0[p], wt[p]);
      f = fmaf(pv, lv, f);
    }
    out[(size_t)pid * CCH + c] = f;
  }
}

extern "C" void kernel_launch(void* const* d_in, const int* in_sizes, int n_in,
                              void* d_out, int out_size, void* d_ws, size_t ws_size,
                              hipStream_t stream) {
  const float* coords = (const float*)d_in[0];
  const float* pyz = (const float*)d_in[1];
  const float* pzx = (const float*)d_in[2];
  const float* pxy = (const float*)d_in[3];
  const float* lx  = (const float*)d_in[4];
  const float* ly  = (const float*)d_in[5];
  const float* lz  = (const float*)d_in[6];
  float* out = (float*)d_out;
  int npts = in_sizes[0] / 3;

  int nsb = (npts + SBP - 1) / SBP;                          // superblocks
  size_t tablesU = 3 * (size_t)PS + 3 * (size_t)LS;          // uints
  size_t needBase   = tablesU * 4u;                          // ~59.7 MB
  size_t needSorted = (tablesU + (size_t)nsb * KB + 2 * KB + (size_t)npts * 4) * 4u;

  if (ws_size >= needSorted) {
    uint32_t* ws = (uint32_t*)d_ws;
    uint32_t* hb = ws + tablesU;                             // [nsb][KB]
    uint32_t* T  = hb + (size_t)nsb * KB;                    // [KB]
    uint32_t* sorted = T + 2 * KB;                           // [npts*4]

    int gx = PH > nsb ? PH : nsb;
    prep_all<<<dim3(gx, 5), 256, 0, stream>>>(pyz, pzx, pxy, lx, ly, lz, ws,
                                              coords, hb, npts, nsb);
    scan_cols<<<(KB + 255) / 256, 256, 0, stream>>>(hb, T, nsb);
    scatter_sb<<<nsb, 256, 0, stream>>>(coords, hb, T, sorted, npts);
    int nwg = (npts + 63) / 64;                              // 64 points per block (4 lanes/pt)
    nwg = (nwg + 7) & ~7;                                    // multiple of 8 for swizzle
    tensorf_sorted4<<<nwg, 256, 0, stream>>>((const uint4*)sorted, ws, out, npts, nwg);
  } else if (ws_size >= needBase) {
    uint32_t* ws = (uint32_t*)d_ws;
    prep_all<<<dim3(PH, 4), 256, 0, stream>>>(pyz, pzx, pxy, lx, ly, lz, ws,
                                              nullptr, nullptr, npts, 0);
    int nthreads = npts * 2;
    tensorf_main<<<(nthreads + 255) / 256, 256, 0, stream>>>(coords, ws, out, npts);
  } else {
    tensorf_fallback<<<(npts + 255) / 256, 256, 0, stream>>>(coords, pyz, pzx, pxy, lx, ly, lz, out, npts);
  }
}

// Round 15
// 344.213 us; speedup vs baseline: 1.4332x; 1.3523x over previous
//
#include <hip/hip_runtime.h>
#include <stdint.h>

#define RES   320
#define CCH   48
#define PW    321                  // padded pair-index width: j = x0+1 in [0,320]
#define PH    322                  // rows jy in [0,321]; rows 0 and 321 are zero
#define PS    (PH*PW*CCH)          // uints per transposed plane (4,961,376)
#define LS    (PW*CCH)             // uints per transposed line  (15,408)
#define KB    512                  // 8^3 Morton cells
#define SBP   8192                 // points per superblock

typedef _Float16 v2h __attribute__((ext_vector_type(2)));
typedef float    f4v __attribute__((ext_vector_type(4)));

__device__ __forceinline__ v2h bch(uint32_t u) { return __builtin_bit_cast(v2h, u); }
__device__ __forceinline__ int clampi(int v, int lo, int hi) { return v < lo ? lo : (v > hi ? hi : v); }

#if __has_builtin(__builtin_amdgcn_fdot2)
__device__ __forceinline__ float fdot2f(v2h a, v2h b, float c) {
  return __builtin_amdgcn_fdot2(a, b, c, false);
}
#else
__device__ __forceinline__ float fdot2f(v2h a, v2h b, float c) {
  return fmaf((float)a.x, (float)b.x, fmaf((float)a.y, (float)b.y, c));
}
#endif

#if __has_builtin(__builtin_amdgcn_cvt_pkrtz)
__device__ __forceinline__ v2h pkw(float a, float b) {
  return __builtin_bit_cast(v2h, __builtin_amdgcn_cvt_pkrtz(a, b));
}
#else
__device__ __forceinline__ v2h pkw(float a, float b) { v2h r; r.x = (_Float16)a; r.y = (_Float16)b; return r; }
#endif

__device__ __forceinline__ uint16_t h16(float a) {
  return __builtin_bit_cast(uint16_t, (_Float16)a);
}

__device__ __forceinline__ void nt_store4(float* p, f4v v) {
  __builtin_nontemporal_store(v, (f4v*)p);
}

// ---- fused prep: planes (y=0..2), lines (y=3), per-superblock hist (y=4) ----
__global__ __launch_bounds__(256) void prep_all(const float* __restrict__ pyz,
                                                const float* __restrict__ pzx,
                                                const float* __restrict__ pxy,
                                                const float* __restrict__ lx,
                                                const float* __restrict__ ly,
                                                const float* __restrict__ lz,
                                                uint32_t* __restrict__ dst,
                                                const float* __restrict__ coords,
                                                uint32_t* __restrict__ hb,
                                                int npts, int nsb);

// ---------------- Morton key: 3 bits/axis, 512 cells ----------------
__device__ __forceinline__ uint32_t part1by2(uint32_t x) {
  x &= 0x3FF;
  x = (x | (x << 16)) & 0x030000FF;
  x = (x | (x << 8))  & 0x0300F00F;
  x = (x | (x << 4))  & 0x030C30C3;
  x = (x | (x << 2))  & 0x09249249;
  return x;
}
__device__ __forceinline__ uint32_t cellkey(float x, float y, float z) {
  int cx = clampi((int)fmaf(x, 4.f, 4.f), 0, 7);
  int cy = clampi((int)fmaf(y, 4.f, 4.f), 0, 7);
  int cz = clampi((int)fmaf(z, 4.f, 4.f), 0, 7);
  return part1by2((uint32_t)cx) | (part1by2((uint32_t)cy) << 1) | (part1by2((uint32_t)cz) << 2);
}

__global__ __launch_bounds__(256) void prep_all(const float* __restrict__ pyz,
                                                const float* __restrict__ pzx,
                                                const float* __restrict__ pxy,
                                                const float* __restrict__ lx,
                                                const float* __restrict__ ly,
                                                const float* __restrict__ lz,
                                                uint32_t* __restrict__ dst,
                                                const float* __restrict__ coords,
                                                uint32_t* __restrict__ hb,
                                                int npts, int nsb) {
  __shared__ __align__(16) char smem[322 * 50 * 2];   // union: lsh (32.2KB) / lh (2KB)
  int tid = threadIdx.x;
  int plane = blockIdx.y;

  if (plane == 4) {                 // per-superblock LDS histogram
    if (hb == nullptr) return;
    int sb = blockIdx.x;
    if (sb >= nsb) return;
    uint32_t* lh = (uint32_t*)smem;
    for (int i = tid; i < KB; i += 256) lh[i] = 0u;
    __syncthreads();
    int base = sb * SBP;
#pragma unroll 4
    for (int k = 0; k < SBP / 256; k++) {
      int p = base + k * 256 + tid;
      if (p < npts) {
        float x = coords[p * 3 + 0], y = coords[p * 3 + 1], z = coords[p * 3 + 2];
        atomicAdd(&lh[cellkey(x, y, z)], 1u);
      }
    }
    __syncthreads();
    uint32_t* d = hb + (size_t)sb * KB;
    for (int i = tid; i < KB; i += 256) d[i] = lh[i];
    return;
  }

  if (plane == 3) {                 // pack lines
    int idx = blockIdx.x * 256 + tid;        // line entries: 3 * PW = 963
    if (idx >= 3 * PW) return;
    int which = idx / PW;
    int j = idx - which * PW;
    const float* src = (which == 0) ? lx : ((which == 1) ? ly : lz);
    uint32_t* d = dst + 3 * (size_t)PS + (size_t)which * LS + (size_t)j * CCH;
    int  y0 = j - 1;
    bool v0 = (y0 >= 0);
    bool v1 = (j < RES);
#pragma unroll
    for (int c = 0; c < CCH; c++) {
      float a = v0 ? src[c * RES + y0] : 0.f;
      float b = v1 ? src[c * RES + j] : 0.f;
      d[c] = (uint32_t)h16(a) | ((uint32_t)h16(b) << 16);
    }
    return;
  }

  int jy = blockIdx.x;              // 0..PH-1
  const float* src = (plane == 0) ? pyz : ((plane == 1) ? pzx : pxy);
  uint32_t* d = dst + (size_t)plane * PS + (size_t)jy * PW * CCH;
  int y = jy - 1;

  if ((unsigned)y >= (unsigned)RES) {           // zero row
    for (int i = tid; i < PW * (CCH / 4); i += 256)
      *(uint4*)(d + i * 4) = make_uint4(0u, 0u, 0u, 0u);
    return;
  }

  // lsh[s][c]: s = x+1 in [0,321], sentinel rows 0 and 321 are zero. stride 50.
  _Float16* lsh = (_Float16*)smem;
  if (tid < 50) { lsh[tid] = (_Float16)0.f; lsh[321 * 50 + tid] = (_Float16)0.f; }
  for (int i = tid; i < CCH * RES; i += 256) {
    int c = i / RES;
    int x = i - c * RES;
    lsh[(x + 1) * 50 + c] = (_Float16)src[(size_t)c * RES * RES + (size_t)y * RES + x];
  }
  __syncthreads();

  // pack: entry (jx, c) = (v[x=jx-1], v[x=jx]) = (lsh[jx][c], lsh[jx+1][c])
  for (int i = tid; i < PW * (CCH / 4); i += 256) {
    int jx = i / (CCH / 4);
    int cb = (i - jx * (CCH / 4)) * 4;
    const _Float16* lo = &lsh[jx * 50 + cb];
    const _Float16* hi = &lsh[(jx + 1) * 50 + cb];
    uint32_t w[4];
#pragma unroll
    for (int k = 0; k < 4; k++)
      w[k] = (uint32_t)__builtin_bit_cast(uint16_t, lo[k]) |
             ((uint32_t)__builtin_bit_cast(uint16_t, hi[k]) << 16);
    *(uint4*)(d + (size_t)(jx * CCH + cb)) = make_uint4(w[0], w[1], w[2], w[3]);
  }
}

// Phase B1: per-bin running prefix across superblocks; emit totals T[bin]
__global__ __launch_bounds__(256) void scan_cols(uint32_t* __restrict__ hb,
                                                 uint32_t* __restrict__ T, int nsb) {
  int b = blockIdx.x * 256 + threadIdx.x;     // bin id
  if (b >= KB) return;
  uint32_t run = 0;
  for (int sb = 0; sb < nsb; sb++) {
    size_t idx = (size_t)sb * KB + b;
    uint32_t v = hb[idx];
    hb[idx] = run;                             // exclusive prefix over superblocks
    run += v;
  }
  T[b] = run;
}

// Phase B2: exclusive scan of T[KB] -> S[KB] (one block)
__global__ __launch_bounds__(256) void scan_T(const uint32_t* __restrict__ T,
                                              uint32_t* __restrict__ S) {
  __shared__ uint32_t bs[256];
  int tid = threadIdx.x;
  uint32_t loc[KB / 256];
  uint32_t s = 0;
#pragma unroll
  for (int k = 0; k < KB / 256; k++) { loc[k] = T[tid * (KB / 256) + k]; s += loc[k]; }
  bs[tid] = s;
  __syncthreads();
  for (int off = 1; off < 256; off <<= 1) {
    uint32_t u = (tid >= off) ? bs[tid - off] : 0u;
    __syncthreads();
    bs[tid] += u;
    __syncthreads();
  }
  uint32_t ex = tid ? bs[tid - 1] : 0u;
#pragma unroll
  for (int k = 0; k < KB / 256; k++) { S[tid * (KB / 256) + k] = ex; ex += loc[k]; }
}

// Phase C: scatter with LDS counters seeded S[bin] + hb[sb][bin]
__global__ __launch_bounds__(256) void scatter_sb(const float* __restrict__ coords,
                                                  const uint32_t* __restrict__ hb,
                                                  const uint32_t* __restrict__ S,
                                                  uint4* __restrict__ sorted, int npts) {
  __shared__ uint32_t cnt[KB];
  int sb = blockIdx.x, tid = threadIdx.x;
  const uint32_t* row = hb + (size_t)sb * KB;
  for (int i = tid; i < KB; i += 256) cnt[i] = row[i] + S[i];
  __syncthreads();
  int base = sb * SBP;
#pragma unroll 4
  for (int k = 0; k < SBP / 256; k++) {
    int p = base + k * 256 + tid;
    if (p < npts) {
      float x = coords[p * 3 + 0], y = coords[p * 3 + 1], z = coords[p * 3 + 2];
      uint32_t pos = atomicAdd(&cnt[cellkey(x, y, z)], 1u);
      if (pos < (uint32_t)npts) {   // guard: corruption -> wrong answer, not OOB write
        uint4 o;
        o.x = __builtin_bit_cast(uint32_t, x);
        o.y = __builtin_bit_cast(uint32_t, y);
        o.z = __builtin_bit_cast(uint32_t, z);
        o.w = (uint32_t)p;
        sorted[pos] = o;
      }
    }
  }
}

// -------- per-plane sampling params (pointers + packed weights) --------
struct PP {
  const uint32_t* rA;
  const uint32_t* rB;
  const uint32_t* lr;
  v2h W0, W1, WT;
};

__device__ __forceinline__ PP mkpp(const uint32_t* __restrict__ P,
                                   const uint32_t* __restrict__ L,
                                   float gx, float gy, float tt) {
  float ix = fmaf(gx, 160.f, 159.5f);
  float fx = floorf(ix); float wx = ix - fx; int jx = clampi((int)fx + 1, 0, 320);
  float iy = fmaf(gy, 160.f, 159.5f);
  float fy = floorf(iy); float wy = iy - fy; int jy = clampi((int)fy + 1, 0, 320);
  float it = fmaf(tt, 160.f, 159.5f);
  float ft = floorf(it); float wt = it - ft; int jt = clampi((int)ft + 1, 0, 320);
  float omx = 1.f - wx, omy = 1.f - wy;
  PP p;
  p.W0 = pkw(omx * omy, wx * omy);
  p.W1 = pkw(omx * wy, wx * wy);
  p.WT = pkw(1.f - wt, wt);
  p.rA = P + (size_t)(jy * PW + jx) * CCH;
  p.rB = p.rA + PW * CCH;
  p.lr = L + (size_t)jt * CCH;
  return p;
}

// per-channel-quad accumulate for one plane
#define ACC4(A, B, LV, W0_, W1_, WT_, ai)                                   \
  {                                                                          \
    float s, lv;                                                             \
    s = fdot2f(bch((A).x), (W0_), 0.f); s = fdot2f(bch((B).x), (W1_), s);    \
    lv = fdot2f(bch((LV).x), (WT_), 0.f); acc[(ai)+0] = fmaf(s, lv, acc[(ai)+0]); \
    s = fdot2f(bch((A).y), (W0_), 0.f); s = fdot2f(bch((B).y), (W1_), s);    \
    lv = fdot2f(bch((LV).y), (WT_), 0.f); acc[(ai)+1] = fmaf(s, lv, acc[(ai)+1]); \
    s = fdot2f(bch((A).z), (W0_), 0.f); s = fdot2f(bch((B).z), (W1_), s);    \
    lv = fdot2f(bch((LV).z), (WT_), 0.f); acc[(ai)+2] = fmaf(s, lv, acc[(ai)+2]); \
    s = fdot2f(bch((A).w), (W0_), 0.f); s = fdot2f(bch((B).w), (W1_), s);    \
    lv = fdot2f(bch((LV).w), (WT_), 0.f); acc[(ai)+3] = fmaf(s, lv, acc[(ai)+3]); \
  }

// ---------------- main: 4 lanes/point, direct full-line NT stores (no LDS) ----------------
__global__ __launch_bounds__(256) void tensorf_sorted4(const uint4* __restrict__ sp,
                                                       const uint32_t* __restrict__ ws,
                                                       float* __restrict__ out,
                                                       int npts, int nwg) {
  int cpx = nwg >> 3;
  int bid = blockIdx.x;
  int swz = (bid & 7) * cpx + (bid >> 3);     // XCD k owns contiguous sorted chunk
  int tid = threadIdx.x;
  int pt = tid >> 2;                  // point slot in block (0..63)
  int q  = tid & 3;                   // lane within point
  int i  = swz * 64 + pt;             // sorted point index
  if (i >= npts) return;

  uint4 s4 = sp[i];
  float x = __builtin_bit_cast(float, s4.x);
  float y = __builtin_bit_cast(float, s4.y);
  float z = __builtin_bit_cast(float, s4.z);
  int pid = (int)s4.w;
  if ((unsigned)pid >= (unsigned)npts) return;   // guard: no OOB write ever

  const uint32_t* P0 = ws;
  const uint32_t* P1 = ws + PS;
  const uint32_t* P2 = ws + 2 * (size_t)PS;
  const uint32_t* L0 = ws + 3 * (size_t)PS;
  const uint32_t* L1 = L0 + LS;
  const uint32_t* L2 = L1 + LS;

  PP p0 = mkpp(P0, L0, y, z, x);   // plane_yz: gx=y, gy=z; line_x(t=x)
  PP p1 = mkpp(P1, L1, z, x, y);   // plane_zx: gx=z, gy=x; line_y(t=y)
  PP p2 = mkpp(P2, L2, x, y, z);   // plane_xy: gx=x, gy=y; line_z(t=z)

  float acc[12];
#pragma unroll
  for (int k = 0; k < 12; k++) acc[k] = 0.f;

#pragma unroll
  for (int j = 0; j < 3; j++) {
    int off = (4 * j + q) * 4;        // 4 lanes cover one 64B line per row per j
    uint4 a0 = *(const uint4*)(p0.rA + off);
    uint4 b0 = *(const uint4*)(p0.rB + off);
    uint4 l0 = *(const uint4*)(p0.lr + off);
    uint4 a1 = *(const uint4*)(p1.rA + off);
    uint4 b1 = *(const uint4*)(p1.rB + off);
    uint4 l1 = *(const uint4*)(p1.lr + off);
    uint4 a2 = *(const uint4*)(p2.rA + off);
    uint4 b2 = *(const uint4*)(p2.rB + off);
    uint4 l2 = *(const uint4*)(p2.lr + off);
    int ai = j * 4;
    ACC4(a0, b0, l0, p0.W0, p0.W1, p0.WT, ai);
    ACC4(a1, b1, l1, p1.W0, p1.W1, p1.WT, ai);
    ACC4(a2, b2, l2, p2.W0, p2.W1, p2.WT, ai);
  }

  // direct NT stores: for fixed j, the 4 lanes of this point write one full
  // 64B line. No LDS staging, no write amplification.
  float* o = out + (size_t)pid * CCH;
#pragma unroll
  for (int j = 0; j < 3; j++) {
    f4v v = { acc[j * 4 + 0], acc[j * 4 + 1], acc[j * 4 + 2], acc[j * 4 + 3] };
    nt_store4(o + (4 * j + q) * 4, v);
  }
}

// ---------------- main (unsorted fallback, proven path, 2 lanes/pt) ----------------
__global__ __launch_bounds__(256) void tensorf_main(const float* __restrict__ coords,
                                                    const uint32_t* __restrict__ ws,
                                                    float* __restrict__ out, int npts) {
  int t = blockIdx.x * 256 + threadIdx.x;
  int pid = t >> 1;
  int q = t & 1;
  if (pid >= npts) return;
  float x = coords[pid * 3 + 0];
  float y = coords[pid * 3 + 1];
  float z = coords[pid * 3 + 2];

  const uint32_t* P0 = ws;
  const uint32_t* P1 = ws + PS;
  const uint32_t* P2 = ws + 2 * (size_t)PS;
  const uint32_t* L0 = ws + 3 * (size_t)PS;
  const uint32_t* L1 = L0 + LS;
  const uint32_t* L2 = L1 + LS;

  PP p0 = mkpp(P0, L0, y, z, x);
  PP p1 = mkpp(P1, L1, z, x, y);
  PP p2 = mkpp(P2, L2, x, y, z);

  float acc[24];
#pragma unroll
  for (int k = 0; k < 24; k++) acc[k] = 0.f;

#pragma unroll
  for (int j = 0; j < 6; j++) {
    int off = (2 * j + q) * 4;
    uint4 a0 = *(const uint4*)(p0.rA + off);
    uint4 b0 = *(const uint4*)(p0.rB + off);
    uint4 l0 = *(const uint4*)(p0.lr + off);
    uint4 a1 = *(const uint4*)(p1.rA + off);
    uint4 b1 = *(const uint4*)(p1.rB + off);
    uint4 l1 = *(const uint4*)(p1.lr + off);
    uint4 a2 = *(const uint4*)(p2.rA + off);
    uint4 b2 = *(const uint4*)(p2.rB + off);
    uint4 l2 = *(const uint4*)(p2.lr + off);
    int ai = j * 4;
    ACC4(a0, b0, l0, p0.W0, p0.W1, p0.WT, ai);
    ACC4(a1, b1, l1, p1.W0, p1.W1, p1.WT, ai);
    ACC4(a2, b2, l2, p2.W0, p2.W1, p2.WT, ai);
  }

  float4* o = (float4*)(out + (size_t)pid * CCH);
#pragma unroll
  for (int j = 0; j < 6; j++) {
    float4 v;
    v.x = acc[j * 4 + 0]; v.y = acc[j * 4 + 1];
    v.z = acc[j * 4 + 2]; v.w = acc[j * 4 + 3];
    o[2 * j + q] = v;
  }
}

// ---------------- direct fallback (tiny ws): slow, correct ----------------
__device__ __forceinline__ float bil(const float* __restrict__ p, int x0, int y0, float wx, float wy) {
  int x1 = x0 + 1, y1 = y0 + 1;
  bool bx0 = (unsigned)x0 < (unsigned)RES, bx1 = (unsigned)x1 < (unsigned)RES;
  bool by0 = (unsigned)y0 < (unsigned)RES, by1 = (unsigned)y1 < (unsigned)RES;
  float v00 = 0.f, v01 = 0.f, v10 = 0.f, v11 = 0.f;
  if (by0) { const float* r = p + (size_t)y0 * RES; if (bx0) v00 = r[x0]; if (bx1) v01 = r[x1]; }
  if (by1) { const float* r = p + (size_t)y1 * RES; if (bx0) v10 = r[x0]; if (bx1) v11 = r[x1]; }
  return v00 * (1.f - wx) * (1.f - wy) + v01 * wx * (1.f - wy) + v10 * (1.f - wx) * wy + v11 * wx * wy;
}
__device__ __forceinline__ float lin1(const float* __restrict__ l, int y0, float wy) {
  int y1 = y0 + 1;
  float a = ((unsigned)y0 < (unsigned)RES) ? l[y0] : 0.f;
  float b = ((unsigned)y1 < (unsigned)RES) ? l[y1] : 0.f;
  return a * (1.f - wy) + b * wy;
}
__global__ __launch_bounds__(256) void tensorf_fallback(const float* __restrict__ coords,
    const float* __restrict__ pyz, const float* __restrict__ pzx, const float* __restrict__ pxy,
    const float* __restrict__ lx, const float* __restrict__ ly, const float* __restrict__ lz,
    float* __restrict__ out, int npts) {
  int pid = blockIdx.x * 256 + threadIdx.x;
  if (pid >= npts) return;
  float x = coords[pid * 3 + 0], y = coords[pid * 3 + 1], z = coords[pid * 3 + 2];
  float ixs[3], iys[3], its[3];
  ixs[0] = fmaf(y, 160.f, 159.5f); iys[0] = fmaf(z, 160.f, 159.5f); its[0] = fmaf(x, 160.f, 159.5f);
  ixs[1] = fmaf(z, 160.f, 159.5f); iys[1] = fmaf(x, 160.f, 159.5f); its[1] = fmaf(y, 160.f, 159.5f);
  ixs[2] = fmaf(x, 160.f, 159.5f); iys[2] = fmaf(y, 160.f, 159.5f); its[2] = fmaf(z, 160.f, 159.5f);
  int x0[3], y0[3], t0[3]; float wx[3], wyv[3], wt[3];
#pragma unroll
  for (int p = 0; p < 3; p++) {
    float fx = floorf(ixs[p]); wx[p] = ixs[p] - fx; x0[p] = (int)fx;
    float fy = floorf(iys[p]); wyv[p] = iys[p] - fy; y0[p] = (int)fy;
    float ft = floorf(its[p]); wt[p] = its[p] - ft; t0[p] = (int)ft;
  }
  const float* planes[3] = { pyz, pzx, pxy };
  const float* lines[3]  = { lx, ly, lz };
  for (int c = 0; c < CCH; c++) {
    float f = 0.f;
#pragma unroll
    for (int p = 0; p < 3; p++) {
      float pv = bil(planes[p] + (size_t)c * RES * RES, x0[p], y0[p], wx[p], wyv[p]);
      float lv = lin1(lines[p] + (size_t)c * RES, t0[p], wt[p]);
      f = fmaf(pv, lv, f);
    }
    out[(size_t)pid * CCH + c] = f;
  }
}

extern "C" void kernel_launch(void* const* d_in, const int* in_sizes, int n_in,
                              void* d_out, int out_size, void* d_ws, size_t ws_size,
                              hipStream_t stream) {
  const float* coords = (const float*)d_in[0];
  const float* pyz = (const float*)d_in[1];
  const float* pzx = (const float*)d_in[2];
  const float* pxy = (const float*)d_in[3];
  const float* lx  = (const float*)d_in[4];
  const float* ly  = (const float*)d_in[5];
  const float* lz  = (const float*)d_in[6];
  float* out = (float*)d_out;
  int npts = in_sizes[0] / 3;

  int nsb = (npts + SBP - 1) / SBP;                          // superblocks
  size_t tablesU = 3 * (size_t)PS + 3 * (size_t)LS;          // uints
  size_t needBase   = tablesU * 4u;                          // ~59.7 MB
  size_t needSorted = (tablesU + (size_t)nsb * KB + 2 * KB + (size_t)npts * 4) * 4u;

  if (ws_size >= needSorted) {
    uint32_t* ws = (uint32_t*)d_ws;
    uint32_t* hb = ws + tablesU;                             // [nsb][KB]
    uint32_t* T  = hb + (size_t)nsb * KB;                    // [KB]
    uint32_t* S  = T + KB;                                   // [KB]
    uint4* sorted = (uint4*)(S + KB);                        // [npts]

    int gx = PH > nsb ? PH : nsb;
    prep_all<<<dim3(gx, 5), 256, 0, stream>>>(pyz, pzx, pxy, lx, ly, lz, ws,
                                              coords, hb, npts, nsb);
    scan_cols<<<(KB + 255) / 256, 256, 0, stream>>>(hb, T, nsb);
    scan_T<<<1, 256, 0, stream>>>(T, S);
    scatter_sb<<<nsb, 256, 0, stream>>>(coords, hb, S, sorted, npts);
    int nwg = (npts + 63) / 64;                              // 64 points per block (4 lanes/pt)
    nwg = (nwg + 7) & ~7;                                    // multiple of 8 for swizzle
    tensorf_sorted4<<<nwg, 256, 0, stream>>>(sorted, ws, out, npts, nwg);
  } else if (ws_size >= needBase) {
    uint32_t* ws = (uint32_t*)d_ws;
    prep_all<<<dim3(PH, 4), 256, 0, stream>>>(pyz, pzx, pxy, lx, ly, lz, ws,
                                              nullptr, nullptr, npts, 0);
    int nthreads = npts * 2;
    tensorf_main<<<(nthreads + 255) / 256, 256, 0, stream>>>(coords, ws, out, npts);
  } else {
    tensorf_fallback<<<(npts + 255) / 256, 256, 0, stream>>>(coords, pyz, pzx, pxy, lx, ly, lz, out, npts);
  }
}